// Round 1
// baseline (1640.953 us; speedup 1.0000x reference)
//
#include <hip/hip_runtime.h>
#include <hip/hip_bf16.h>
#include <math.h>

#define S_LEN 1024
#define HID 256
#define HEADS 8
#define HD 32
#define NLAYER 4
#define TED 256
#define BATCH 4
#define DECAY 0.1f
#define ATT_SCALE 0.17677669529663687f  // 32^-0.5

__device__ __forceinline__ float gelu_f(float x) {
  return 0.5f * x * (1.f + erff(x * 0.70710678118654752f));
}

// ---------------------------------------------------------------- prep kernel
// te = Lin(mish(Lin(sin_emb(time)))); qe = Lin(gelu(Lin(query)));
// tp[l] = Lin(gelu(Lin(te)))
__global__ __launch_bounds__(1024) void k_prep(
    const float* __restrict__ timev,
    const float* __restrict__ tm_w1, const float* __restrict__ tm_b1,
    const float* __restrict__ tm_w2, const float* __restrict__ tm_b2,
    const float* __restrict__ query,
    const float* __restrict__ q_w1, const float* __restrict__ q_b1,
    const float* __restrict__ q_w2, const float* __restrict__ q_b2,
    const float* __restrict__ t1_w, const float* __restrict__ t1_b,
    const float* __restrict__ t2_w, const float* __restrict__ t2_b,
    float* __restrict__ qe_out, float* __restrict__ tp_out) {
  __shared__ float emb[BATCH][256];   // reused as tt later
  __shared__ float te1[BATCH][1024];
  __shared__ float te[BATCH][256];
  __shared__ float tmp[BATCH][256];
  int tid = threadIdx.x;

  // sinusoidal embedding
  {
    int b = tid >> 8, j = tid & 255;
    float t = timev[b];
    int i = j & 127;
    float freq = expf(-logf(10000.f) * (float)i / 127.f);
    float a = t * freq;
    emb[b][j] = (j < 128) ? sinf(a) : cosf(a);
  }
  __syncthreads();
  // te1 = mish(emb @ tm_w1^T + tm_b1)   [4,1024]
  for (int idx = tid; idx < 4096; idx += 1024) {
    int b = idx >> 10, o = idx & 1023;
    float s = tm_b1[o];
    const float* w = tm_w1 + (size_t)o * 256;
    for (int k = 0; k < 256; k++) s += emb[b][k] * w[k];
    float sp = (s > 20.f) ? s : log1pf(__expf(s));
    te1[b][o] = s * tanhf(sp);
  }
  __syncthreads();
  // te = te1 @ tm_w2^T + tm_b2   [4,256]
  {
    int b = tid >> 8, o = tid & 255;
    float s = tm_b2[o];
    const float* w = tm_w2 + (size_t)o * 1024;
    for (int k = 0; k < 1024; k++) s += te1[b][k] * w[k];
    te[b][o] = s;
  }
  __syncthreads();
  // q1 = gelu(query @ q_w1^T + q_b1) -> tmp
  {
    int b = tid >> 8, o = tid & 255;
    float s = q_b1[o];
    const float* w = q_w1 + (size_t)o * 32;
    for (int k = 0; k < 32; k++) s += query[b * 32 + k] * w[k];
    tmp[b][o] = gelu_f(s);
  }
  __syncthreads();
  // qe = tmp @ q_w2^T + q_b2
  {
    int b = tid >> 8, o = tid & 255;
    float s = q_b2[o];
    const float* w = q_w2 + (size_t)o * 256;
    for (int k = 0; k < 256; k++) s += tmp[b][k] * w[k];
    qe_out[tid] = s;
  }
  // tp per layer (emb buffer reused for tt)
  for (int l = 0; l < NLAYER; l++) {
    __syncthreads();
    {
      int b = tid >> 8, o = tid & 255;
      float s = t1_b[l * 256 + o];
      const float* w = t1_w + ((size_t)l * 256 + o) * 256;
      float acc = s;
      for (int k = 0; k < 256; k++) acc += te[b][k] * w[k];
      emb[b][o] = gelu_f(acc);
    }
    __syncthreads();
    {
      int b = tid >> 8, o = tid & 255;
      float s = t2_b[l * 256 + o];
      const float* w = t2_w + ((size_t)l * 256 + o) * 256;
      for (int k = 0; k < 256; k++) s += emb[b][k] * w[k];
      tp_out[l * 1024 + tid] = s;
    }
  }
}

// ------------------------------------------------------------ input projection
__global__ __launch_bounds__(256) void k_inproj(
    const float* __restrict__ x, const float* __restrict__ in_w,
    const float* __restrict__ in_b, const float* __restrict__ qe,
    float* __restrict__ h) {
  int row = blockIdx.x;  // 0..4095
  int b = row >> 10;
  int j = threadIdx.x;
  __shared__ float xr[16];
  if (j < 16) xr[j] = x[row * 16 + j];
  __syncthreads();
  float s = in_b[j] + qe[b * 256 + j];
  const float* w = in_w + j * 16;
#pragma unroll
  for (int i = 0; i < 16; i++) s += xr[i] * w[i];
  h[(size_t)row * 256 + j] = s;
}

// -------------------------------------------------------------------- layernorm
__global__ __launch_bounds__(256) void k_ln(
    const float* __restrict__ hbuf, const float* __restrict__ tp,
    const float* __restrict__ w, const float* __restrict__ bparm,
    float* __restrict__ out) {
  int row = blockIdx.x, b = row >> 10, tid = threadIdx.x;
  float v = hbuf[(size_t)row * 256 + tid];
  if (tp) v += tp[b * 256 + tid];
  __shared__ float red[4];
  float s = v;
#pragma unroll
  for (int off = 32; off; off >>= 1) s += __shfl_xor(s, off);
  if ((tid & 63) == 0) red[tid >> 6] = s;
  __syncthreads();
  float mean = (red[0] + red[1] + red[2] + red[3]) * (1.f / 256.f);
  float d = v - mean;
  float s2 = d * d;
#pragma unroll
  for (int off = 32; off; off >>= 1) s2 += __shfl_xor(s2, off);
  __syncthreads();
  if ((tid & 63) == 0) red[tid >> 6] = s2;
  __syncthreads();
  float var = (red[0] + red[1] + red[2] + red[3]) * (1.f / 256.f);
  out[(size_t)row * 256 + tid] = d * rsqrtf(var + 1e-5f) * w[tid] + bparm[tid];
}

// ----------------------------------------------------------------------- GEMM
// C[M,N] = A[M,K] @ W[N,K]^T + bias ; ACT=1 -> gelu ; ADD -> C += result
template <int ACT, bool ADD>
__global__ __launch_bounds__(256) void k_gemm(
    const float* __restrict__ A, const float* __restrict__ W,
    const float* __restrict__ bias, float* __restrict__ C,
    int M, int N, int K) {
  __shared__ float a_lds[16][68];
  __shared__ float b_lds[16][68];
  int tid = threadIdx.x;
  int tx = tid & 15, ty = tid >> 4;
  int m0 = blockIdx.y * 64, n0 = blockIdx.x * 64;
  float acc[4][4] = {};
  int lr = tid >> 2;
  int lc = (tid & 3) * 4;
  for (int k0 = 0; k0 < K; k0 += 16) {
    float4 av = *(const float4*)(A + (size_t)(m0 + lr) * K + k0 + lc);
    float4 wv = *(const float4*)(W + (size_t)(n0 + lr) * K + k0 + lc);
    __syncthreads();
    a_lds[lc + 0][lr] = av.x; a_lds[lc + 1][lr] = av.y;
    a_lds[lc + 2][lr] = av.z; a_lds[lc + 3][lr] = av.w;
    b_lds[lc + 0][lr] = wv.x; b_lds[lc + 1][lr] = wv.y;
    b_lds[lc + 2][lr] = wv.z; b_lds[lc + 3][lr] = wv.w;
    __syncthreads();
#pragma unroll
    for (int kk = 0; kk < 16; kk++) {
      float4 a4 = *(const float4*)&a_lds[kk][ty * 4];
      float4 b4 = *(const float4*)&b_lds[kk][tx * 4];
      acc[0][0] += a4.x * b4.x; acc[0][1] += a4.x * b4.y;
      acc[0][2] += a4.x * b4.z; acc[0][3] += a4.x * b4.w;
      acc[1][0] += a4.y * b4.x; acc[1][1] += a4.y * b4.y;
      acc[1][2] += a4.y * b4.z; acc[1][3] += a4.y * b4.w;
      acc[2][0] += a4.z * b4.x; acc[2][1] += a4.z * b4.y;
      acc[2][2] += a4.z * b4.z; acc[2][3] += a4.z * b4.w;
      acc[3][0] += a4.w * b4.x; acc[3][1] += a4.w * b4.y;
      acc[3][2] += a4.w * b4.z; acc[3][3] += a4.w * b4.w;
    }
  }
#pragma unroll
  for (int i = 0; i < 4; i++) {
#pragma unroll
    for (int j = 0; j < 4; j++) {
      int r = m0 + ty * 4 + i, c = n0 + tx * 4 + j;
      float v = acc[i][j] + bias[c];
      if (ACT == 1) v = gelu_f(v);
      size_t idx = (size_t)r * N + c;
      if (ADD) C[idx] += v; else C[idx] = v;
    }
  }
}

// --------------------------------------------------------------- decayed bias
__global__ void k_decbias(const float* __restrict__ relb, float* __restrict__ decb) {
  int i = blockIdx.x * 256 + threadIdx.x;
  if (i < 2047 * 8) {
    int r = i >> 3;
    float dec = __expf(-DECAY * fabsf((float)(r - 1023)));
    decb[i] = dec * relb[i];
  }
}

// ------------------------------------------------------------- flash attention
// qkv: [B,S,3*HID] laid out [3][H][HD] in last dim. obuf: [B,S,HID]
__global__ __launch_bounds__(256) void k_attn(
    const float* __restrict__ qkv, const float* __restrict__ decb,
    float* __restrict__ obuf) {
  __shared__ float K_lds[128][36];
  __shared__ float V_lds[128][36];
  __shared__ float p_lds[16][132];
  __shared__ float db[1040];
  int tid = threadIdx.x;
  int bh = blockIdx.y;
  int b = bh >> 3, hh = bh & 7;
  int q0 = blockIdx.x * 16;
  int row = tid >> 4, col = tid & 15;
  int q_row = q0 + row;

  // decayed-bias slice: db[i] corresponds to table idx q0+i  (rel+1023)
  for (int i = tid; i < 1039; i += 256) db[i] = decb[(q0 + i) * 8 + hh];

  const float* Qp = qkv + ((size_t)(b * S_LEN + q_row)) * 768 + hh * 32;
  float4 qv[8];
#pragma unroll
  for (int i = 0; i < 8; i++) qv[i] = ((const float4*)Qp)[i];

  float m_run = -1e30f, ssum = 0.f, o0 = 0.f, o1 = 0.f;
  int d0 = col * 2;

  for (int c0 = 0; c0 < S_LEN; c0 += 128) {
    __syncthreads();
    {
      int krow = tid >> 1, part = tid & 1;
      const float4* Ksrc = (const float4*)(qkv + ((size_t)(b * S_LEN + c0 + krow)) * 768 + 256 + hh * 32 + part * 16);
      const float4* Vsrc = (const float4*)(qkv + ((size_t)(b * S_LEN + c0 + krow)) * 768 + 512 + hh * 32 + part * 16);
#pragma unroll
      for (int i = 0; i < 4; i++) {
        float4 kv = Ksrc[i];
        float4 vv = Vsrc[i];
        int cc = part * 16 + i * 4;
        K_lds[krow][cc + 0] = kv.x; K_lds[krow][cc + 1] = kv.y;
        K_lds[krow][cc + 2] = kv.z; K_lds[krow][cc + 3] = kv.w;
        V_lds[krow][cc + 0] = vv.x; V_lds[krow][cc + 1] = vv.y;
        V_lds[krow][cc + 2] = vv.z; V_lds[krow][cc + 3] = vv.w;
      }
    }
    __syncthreads();
    float sc[8];
    float cmax = -1e30f;
#pragma unroll
    for (int j = 0; j < 8; j++) {
      int kl = col + j * 16;
      int kglob = c0 + kl;
      const float* Kr = &K_lds[kl][0];
      float s = 0.f;
#pragma unroll
      for (int i = 0; i < 8; i++) {
        float4 k4 = *(const float4*)(Kr + i * 4);
        s += qv[i].x * k4.x + qv[i].y * k4.y + qv[i].z * k4.z + qv[i].w * k4.w;
      }
      s = s * ATT_SCALE + db[row + 1023 - kglob];
      sc[j] = s;
      cmax = fmaxf(cmax, s);
    }
#pragma unroll
    for (int off = 1; off < 16; off <<= 1) cmax = fmaxf(cmax, __shfl_xor(cmax, off));
    float mnew = fmaxf(m_run, cmax);
    float resc = __expf(m_run - mnew);
    o0 *= resc; o1 *= resc; ssum *= resc;
    float psum = 0.f;
#pragma unroll
    for (int j = 0; j < 8; j++) {
      float p = __expf(sc[j] - mnew);
      psum += p;
      p_lds[row][col + j * 16] = p;
    }
#pragma unroll
    for (int off = 1; off < 16; off <<= 1) psum += __shfl_xor(psum, off);
    ssum += psum;
    m_run = mnew;
#pragma unroll 4
    for (int k = 0; k < 128; k++) {
      float p = p_lds[row][k];
      float2 v2 = *(const float2*)&V_lds[k][d0];
      o0 += p * v2.x;
      o1 += p * v2.y;
    }
  }
  float inv = 1.f / ssum;
  float2 res = make_float2(o0 * inv, o1 * inv);
  *(float2*)(obuf + ((size_t)(b * S_LEN + q_row)) * 256 + hh * 32 + d0) = res;
}

// ------------------------------------------------------------------- final out
__global__ __launch_bounds__(256) void k_out(
    const float* __restrict__ hbuf, const float* __restrict__ out_w,
    const float* __restrict__ out_b, float* __restrict__ out) {
  int tid = threadIdx.x;
  int r = blockIdx.x * 16 + (tid >> 4);
  int c = tid & 15;
  const float* hr = hbuf + (size_t)r * 256;
  const float* w = out_w + c * 256;
  float s = out_b[c];
  for (int k = 0; k < 256; k++) s += hr[k] * w[k];
  out[r * 16 + c] = s;
}

// ------------------------------------------------------------------ host side
extern "C" void kernel_launch(void* const* d_in, const int* in_sizes, int n_in,
                              void* d_out, int out_size, void* d_ws, size_t ws_size,
                              hipStream_t stream) {
  const float* x      = (const float*)d_in[0];
  const float* query  = (const float*)d_in[1];
  const float* timev  = (const float*)d_in[2];
  const float* tm_w1  = (const float*)d_in[3];
  const float* tm_b1  = (const float*)d_in[4];
  const float* tm_w2  = (const float*)d_in[5];
  const float* tm_b2  = (const float*)d_in[6];
  const float* in_w   = (const float*)d_in[7];
  const float* in_b   = (const float*)d_in[8];
  const float* q_w1   = (const float*)d_in[9];
  const float* q_b1   = (const float*)d_in[10];
  const float* q_w2   = (const float*)d_in[11];
  const float* q_b2   = (const float*)d_in[12];
  const float* n1_w   = (const float*)d_in[13];
  const float* n1_b   = (const float*)d_in[14];
  const float* qkv_w  = (const float*)d_in[15];
  const float* qkv_b  = (const float*)d_in[16];
  const float* ap_w   = (const float*)d_in[17];
  const float* ap_b   = (const float*)d_in[18];
  const float* relb   = (const float*)d_in[19];
  const float* n2_w   = (const float*)d_in[20];
  const float* n2_b   = (const float*)d_in[21];
  const float* f1_w   = (const float*)d_in[22];
  const float* f1_b   = (const float*)d_in[23];
  const float* f2_w   = (const float*)d_in[24];
  const float* f2_b   = (const float*)d_in[25];
  const float* t1_w   = (const float*)d_in[26];
  const float* t1_b   = (const float*)d_in[27];
  const float* t2_w   = (const float*)d_in[28];
  const float* t2_b   = (const float*)d_in[29];
  const float* out_w  = (const float*)d_in[30];
  const float* out_b  = (const float*)d_in[31];
  float* out = (float*)d_out;

  float* ws = (float*)d_ws;
  float* h    = ws;                       // 4096*256      = 1M floats
  float* xn   = ws + (1u << 20);          // 1M
  float* qkvb = ws + 2 * (1u << 20);      // 4096*768      = 3M
  float* ob   = ws + 5 * (1u << 20);      // 1M
  float* y1   = ws + 6 * (1u << 20);      // 4096*1024     = 4M
  float* decb = ws + 10 * (1u << 20);     // 2047*8
  float* qe   = decb + 16384;             // 1024
  float* tp   = qe + 1024;                // 4*1024

  k_prep<<<1, 1024, 0, stream>>>(timev, tm_w1, tm_b1, tm_w2, tm_b2, query,
                                 q_w1, q_b1, q_w2, q_b2, t1_w, t1_b, t2_w, t2_b,
                                 qe, tp);
  k_inproj<<<4096, 256, 0, stream>>>(x, in_w, in_b, qe, h);

  for (int l = 0; l < NLAYER; l++) {
    k_decbias<<<64, 256, 0, stream>>>(relb + (size_t)l * 2047 * 8, decb);
    k_ln<<<4096, 256, 0, stream>>>(h, tp + l * 1024, n1_w + l * 256, n1_b + l * 256, xn);
    k_gemm<0, false><<<dim3(12, 64), 256, 0, stream>>>(
        xn, qkv_w + (size_t)l * 768 * 256, qkv_b + l * 768, qkvb, 4096, 768, 256);
    k_attn<<<dim3(64, 32), 256, 0, stream>>>(qkvb, decb, ob);
    k_gemm<0, true><<<dim3(4, 64), 256, 0, stream>>>(
        ob, ap_w + (size_t)l * 256 * 256, ap_b + l * 256, h, 4096, 256, 256);
    k_ln<<<4096, 256, 0, stream>>>(h, nullptr, n2_w + l * 256, n2_b + l * 256, xn);
    k_gemm<1, false><<<dim3(16, 64), 256, 0, stream>>>(
        xn, f1_w + (size_t)l * 1024 * 256, f1_b + l * 1024, y1, 4096, 1024, 256);
    k_gemm<0, true><<<dim3(4, 64), 256, 0, stream>>>(
        y1, f2_w + (size_t)l * 256 * 1024, f2_b + l * 256, h, 4096, 256, 1024);
  }
  k_out<<<256, 256, 0, stream>>>(h, out_w, out_b, out);
}

// Round 2
// 1158.912 us; speedup vs baseline: 1.4159x; 1.4159x over previous
//
#include <hip/hip_runtime.h>
#include <hip/hip_bf16.h>
#include <math.h>

#define S_LEN 1024
#define HID 256
#define HEADS 8
#define HD 32
#define NLAYER 4
#define TED 256
#define BATCH 4
#define DECAY 0.1f
#define ATT_SCALE 0.17677669529663687f  // 32^-0.5

__device__ __forceinline__ float gelu_f(float x) {
  return 0.5f * x * (1.f + erff(x * 0.70710678118654752f));
}

// ---------------------------------------------------------------- prep: emb
__global__ __launch_bounds__(256) void k_emb(const float* __restrict__ timev,
                                             float* __restrict__ emb) {
  int b = blockIdx.x, j = threadIdx.x;
  float t = timev[b];
  int i = j & 127;
  float freq = __expf(-logf(10000.f) * (float)i / 127.f);
  float a = t * freq;
  emb[b * 256 + j] = (j < 128) ? sinf(a) : cosf(a);
}

// ------------------------------------------------- wave-parallel GEMV (prep)
// out[r] = act(A[a_row] . W[g*OUT+o] + bias[g*OUT+o])
// r = g*(BATCH*OUT) + b*OUT + o ; a_row = (APG ? g*BATCH : 0) + b
// ACT: 0=none 1=gelu 2=mish
template <int ACT, bool APG>
__global__ __launch_bounds__(256) void k_gemv(
    const float* __restrict__ A, const float* __restrict__ W,
    const float* __restrict__ bias, float* __restrict__ out,
    int K, int OUT) {
  int r = blockIdx.x * 4 + (threadIdx.x >> 6);
  int lane = threadIdx.x & 63;
  int o = r % OUT;
  int b = (r / OUT) % BATCH;
  int g = r / (OUT * BATCH);
  const float* a = A + (size_t)((APG ? g * BATCH : 0) + b) * K;
  const float* w = W + (size_t)(g * OUT + o) * K;
  float s = 0.f;
  for (int k = lane * 4; k < K; k += 256) {
    float4 a4 = *(const float4*)(a + k);
    float4 w4 = *(const float4*)(w + k);
    s += a4.x * w4.x + a4.y * w4.y + a4.z * w4.z + a4.w * w4.w;
  }
#pragma unroll
  for (int off = 32; off; off >>= 1) s += __shfl_xor(s, off);
  if (lane == 0) {
    s += bias[g * OUT + o];
    if (ACT == 1) s = gelu_f(s);
    if (ACT == 2) {
      float sp = (s > 20.f) ? s : log1pf(__expf(s));
      s = s * tanhf(sp);
    }
    out[r] = s;
  }
}

// ------------------------------------------------------------ input projection
__global__ __launch_bounds__(256) void k_inproj(
    const float* __restrict__ x, const float* __restrict__ in_w,
    const float* __restrict__ in_b, const float* __restrict__ qe,
    float* __restrict__ h) {
  int row = blockIdx.x;  // 0..4095
  int b = row >> 10;
  int j = threadIdx.x;
  __shared__ float xr[16];
  if (j < 16) xr[j] = x[row * 16 + j];
  __syncthreads();
  float s = in_b[j] + qe[b * 256 + j];
  const float* w = in_w + j * 16;
#pragma unroll
  for (int i = 0; i < 16; i++) s += xr[i] * w[i];
  h[(size_t)row * 256 + j] = s;
}

// -------------------------------------------------------------------- layernorm
__global__ __launch_bounds__(256) void k_ln(
    const float* __restrict__ hbuf, const float* __restrict__ tp,
    const float* __restrict__ w, const float* __restrict__ bparm,
    float* __restrict__ out) {
  int row = blockIdx.x, b = row >> 10, tid = threadIdx.x;
  float v = hbuf[(size_t)row * 256 + tid];
  if (tp) v += tp[b * 256 + tid];
  __shared__ float red[4];
  float s = v;
#pragma unroll
  for (int off = 32; off; off >>= 1) s += __shfl_xor(s, off);
  if ((tid & 63) == 0) red[tid >> 6] = s;
  __syncthreads();
  float mean = (red[0] + red[1] + red[2] + red[3]) * (1.f / 256.f);
  float d = v - mean;
  float s2 = d * d;
#pragma unroll
  for (int off = 32; off; off >>= 1) s2 += __shfl_xor(s2, off);
  __syncthreads();
  if ((tid & 63) == 0) red[tid >> 6] = s2;
  __syncthreads();
  float var = (red[0] + red[1] + red[2] + red[3]) * (1.f / 256.f);
  out[(size_t)row * 256 + tid] = d * rsqrtf(var + 1e-5f) * w[tid] + bparm[tid];
}

// ----------------------------------------------------------------------- GEMM
// C[M,N] = A[M,K] @ W[N,K]^T + bias ; ACT=1 -> gelu ; ADD -> C += result
template <int ACT, bool ADD>
__global__ __launch_bounds__(256) void k_gemm(
    const float* __restrict__ A, const float* __restrict__ W,
    const float* __restrict__ bias, float* __restrict__ C,
    int M, int N, int K) {
  __shared__ float a_lds[16][68];
  __shared__ float b_lds[16][68];
  int tid = threadIdx.x;
  int tx = tid & 15, ty = tid >> 4;
  int m0 = blockIdx.y * 64, n0 = blockIdx.x * 64;
  float acc[4][4] = {};
  int lr = tid >> 2;
  int lc = (tid & 3) * 4;
  for (int k0 = 0; k0 < K; k0 += 16) {
    float4 av = *(const float4*)(A + (size_t)(m0 + lr) * K + k0 + lc);
    float4 wv = *(const float4*)(W + (size_t)(n0 + lr) * K + k0 + lc);
    __syncthreads();
    a_lds[lc + 0][lr] = av.x; a_lds[lc + 1][lr] = av.y;
    a_lds[lc + 2][lr] = av.z; a_lds[lc + 3][lr] = av.w;
    b_lds[lc + 0][lr] = wv.x; b_lds[lc + 1][lr] = wv.y;
    b_lds[lc + 2][lr] = wv.z; b_lds[lc + 3][lr] = wv.w;
    __syncthreads();
#pragma unroll
    for (int kk = 0; kk < 16; kk++) {
      float4 a4 = *(const float4*)&a_lds[kk][ty * 4];
      float4 b4 = *(const float4*)&b_lds[kk][tx * 4];
      acc[0][0] += a4.x * b4.x; acc[0][1] += a4.x * b4.y;
      acc[0][2] += a4.x * b4.z; acc[0][3] += a4.x * b4.w;
      acc[1][0] += a4.y * b4.x; acc[1][1] += a4.y * b4.y;
      acc[1][2] += a4.y * b4.z; acc[1][3] += a4.y * b4.w;
      acc[2][0] += a4.z * b4.x; acc[2][1] += a4.z * b4.y;
      acc[2][2] += a4.z * b4.z; acc[2][3] += a4.z * b4.w;
      acc[3][0] += a4.w * b4.x; acc[3][1] += a4.w * b4.y;
      acc[3][2] += a4.w * b4.z; acc[3][3] += a4.w * b4.w;
    }
  }
#pragma unroll
  for (int i = 0; i < 4; i++) {
#pragma unroll
    for (int j = 0; j < 4; j++) {
      int r = m0 + ty * 4 + i, c = n0 + tx * 4 + j;
      float v = acc[i][j] + bias[c];
      if (ACT == 1) v = gelu_f(v);
      size_t idx = (size_t)r * N + c;
      if (ADD) C[idx] += v; else C[idx] = v;
    }
  }
}

// --------------------------------------------------------------- decayed bias
__global__ void k_decbias(const float* __restrict__ relb, float* __restrict__ decb) {
  int i = blockIdx.x * 256 + threadIdx.x;
  if (i < 2047 * 8) {
    int r = i >> 3;
    float dec = __expf(-DECAY * fabsf((float)(r - 1023)));
    decb[i] = dec * relb[i];
  }
}

// ------------------------------------------------------------- flash attention
// qkv: [B,S,3*HID] laid out [3][H][HD] in last dim. obuf: [B,S,HID]
__global__ __launch_bounds__(256) void k_attn(
    const float* __restrict__ qkv, const float* __restrict__ decb,
    float* __restrict__ obuf) {
  __shared__ float K_lds[128][36];
  __shared__ float V_lds[128][36];
  __shared__ float p_lds[16][132];
  __shared__ float db[1040];
  int tid = threadIdx.x;
  int bh = blockIdx.y;
  int b = bh >> 3, hh = bh & 7;
  int q0 = blockIdx.x * 16;
  int row = tid >> 4, col = tid & 15;
  int q_row = q0 + row;

  // decayed-bias slice: db[i] corresponds to table idx q0+i  (rel+1023)
  for (int i = tid; i < 1039; i += 256) db[i] = decb[(q0 + i) * 8 + hh];

  const float* Qp = qkv + ((size_t)(b * S_LEN + q_row)) * 768 + hh * 32;
  float4 qv[8];
#pragma unroll
  for (int i = 0; i < 8; i++) qv[i] = ((const float4*)Qp)[i];

  float m_run = -1e30f, ssum = 0.f, o0 = 0.f, o1 = 0.f;
  int d0 = col * 2;

  for (int c0 = 0; c0 < S_LEN; c0 += 128) {
    __syncthreads();
    {
      int krow = tid >> 1, part = tid & 1;
      const float4* Ksrc = (const float4*)(qkv + ((size_t)(b * S_LEN + c0 + krow)) * 768 + 256 + hh * 32 + part * 16);
      const float4* Vsrc = (const float4*)(qkv + ((size_t)(b * S_LEN + c0 + krow)) * 768 + 512 + hh * 32 + part * 16);
#pragma unroll
      for (int i = 0; i < 4; i++) {
        float4 kv = Ksrc[i];
        float4 vv = Vsrc[i];
        int cc = part * 16 + i * 4;
        K_lds[krow][cc + 0] = kv.x; K_lds[krow][cc + 1] = kv.y;
        K_lds[krow][cc + 2] = kv.z; K_lds[krow][cc + 3] = kv.w;
        V_lds[krow][cc + 0] = vv.x; V_lds[krow][cc + 1] = vv.y;
        V_lds[krow][cc + 2] = vv.z; V_lds[krow][cc + 3] = vv.w;
      }
    }
    __syncthreads();
    float sc[8];
    float cmax = -1e30f;
#pragma unroll
    for (int j = 0; j < 8; j++) {
      int kl = col + j * 16;
      int kglob = c0 + kl;
      const float* Kr = &K_lds[kl][0];
      float s = 0.f;
#pragma unroll
      for (int i = 0; i < 8; i++) {
        float4 k4 = *(const float4*)(Kr + i * 4);
        s += qv[i].x * k4.x + qv[i].y * k4.y + qv[i].z * k4.z + qv[i].w * k4.w;
      }
      s = s * ATT_SCALE + db[row + 1023 - kglob];
      sc[j] = s;
      cmax = fmaxf(cmax, s);
    }
#pragma unroll
    for (int off = 1; off < 16; off <<= 1) cmax = fmaxf(cmax, __shfl_xor(cmax, off));
    float mnew = fmaxf(m_run, cmax);
    float resc = __expf(m_run - mnew);
    o0 *= resc; o1 *= resc; ssum *= resc;
    float psum = 0.f;
#pragma unroll
    for (int j = 0; j < 8; j++) {
      float p = __expf(sc[j] - mnew);
      psum += p;
      p_lds[row][col + j * 16] = p;
    }
#pragma unroll
    for (int off = 1; off < 16; off <<= 1) psum += __shfl_xor(psum, off);
    ssum += psum;
    m_run = mnew;
#pragma unroll 4
    for (int k = 0; k < 128; k++) {
      float p = p_lds[row][k];
      float2 v2 = *(const float2*)&V_lds[k][d0];
      o0 += p * v2.x;
      o1 += p * v2.y;
    }
  }
  float inv = 1.f / ssum;
  float2 res = make_float2(o0 * inv, o1 * inv);
  *(float2*)(obuf + ((size_t)(b * S_LEN + q_row)) * 256 + hh * 32 + d0) = res;
}

// ------------------------------------------------------------------- final out
__global__ __launch_bounds__(256) void k_out(
    const float* __restrict__ hbuf, const float* __restrict__ out_w,
    const float* __restrict__ out_b, float* __restrict__ out) {
  int tid = threadIdx.x;
  int r = blockIdx.x * 16 + (tid >> 4);
  int c = tid & 15;
  const float* hr = hbuf + (size_t)r * 256;
  const float* w = out_w + c * 256;
  float s = out_b[c];
  for (int k = 0; k < 256; k++) s += hr[k] * w[k];
  out[r * 16 + c] = s;
}

// ------------------------------------------------------------------ host side
extern "C" void kernel_launch(void* const* d_in, const int* in_sizes, int n_in,
                              void* d_out, int out_size, void* d_ws, size_t ws_size,
                              hipStream_t stream) {
  const float* x      = (const float*)d_in[0];
  const float* query  = (const float*)d_in[1];
  const float* timev  = (const float*)d_in[2];
  const float* tm_w1  = (const float*)d_in[3];
  const float* tm_b1  = (const float*)d_in[4];
  const float* tm_w2  = (const float*)d_in[5];
  const float* tm_b2  = (const float*)d_in[6];
  const float* in_w   = (const float*)d_in[7];
  const float* in_b   = (const float*)d_in[8];
  const float* q_w1   = (const float*)d_in[9];
  const float* q_b1   = (const float*)d_in[10];
  const float* q_w2   = (const float*)d_in[11];
  const float* q_b2   = (const float*)d_in[12];
  const float* n1_w   = (const float*)d_in[13];
  const float* n1_b   = (const float*)d_in[14];
  const float* qkv_w  = (const float*)d_in[15];
  const float* qkv_b  = (const float*)d_in[16];
  const float* ap_w   = (const float*)d_in[17];
  const float* ap_b   = (const float*)d_in[18];
  const float* relb   = (const float*)d_in[19];
  const float* n2_w   = (const float*)d_in[20];
  const float* n2_b   = (const float*)d_in[21];
  const float* f1_w   = (const float*)d_in[22];
  const float* f1_b   = (const float*)d_in[23];
  const float* f2_w   = (const float*)d_in[24];
  const float* f2_b   = (const float*)d_in[25];
  const float* t1_w   = (const float*)d_in[26];
  const float* t1_b   = (const float*)d_in[27];
  const float* t2_w   = (const float*)d_in[28];
  const float* t2_b   = (const float*)d_in[29];
  const float* out_w  = (const float*)d_in[30];
  const float* out_b  = (const float*)d_in[31];
  float* out = (float*)d_out;

  float* ws = (float*)d_ws;
  float* h    = ws;                       // 4096*256      = 1M floats
  float* xn   = ws + (1u << 20);          // 1M
  float* qkvb = ws + 2 * (1u << 20);      // 4096*768      = 3M
  float* ob   = ws + 5 * (1u << 20);      // 1M
  float* y1   = ws + 6 * (1u << 20);      // 4096*1024     = 4M
  float* decb = ws + 10 * (1u << 20);     // 2047*8
  float* qe   = decb + 16384;             // 1024
  float* tp   = qe + 1024;                // 4*1024

  // prep scratch lives inside qkvb (unused until first k_gemm of layer 0)
  float* emb = qkvb;                      // 1024
  float* te1 = qkvb + 1024;               // 4096
  float* te  = qkvb + 5120;               // 1024
  float* q1  = qkvb + 6144;               // 1024
  float* tt  = qkvb + 7168;               // 4096

  // ---- prep pipeline (wave-parallel GEMVs) ----
  k_emb<<<4, 256, 0, stream>>>(timev, emb);
  // te1 = mish(emb @ tm_w1^T + tm_b1)   [4,1024], K=256
  k_gemv<2, false><<<1024, 256, 0, stream>>>(emb, tm_w1, tm_b1, te1, 256, 1024);
  // te  = te1 @ tm_w2^T + tm_b2         [4,256], K=1024
  k_gemv<0, false><<<256, 256, 0, stream>>>(te1, tm_w2, tm_b2, te, 1024, 256);
  // q1  = gelu(query @ q_w1^T + q_b1)   [4,256], K=32
  k_gemv<1, false><<<256, 256, 0, stream>>>(query, q_w1, q_b1, q1, 32, 256);
  // qe  = q1 @ q_w2^T + q_b2            [4,256], K=256
  k_gemv<0, false><<<256, 256, 0, stream>>>(q1, q_w2, q_b2, qe, 256, 256);
  // tt[l] = gelu(te @ t1_w[l]^T + t1_b[l])  [4,4,256], K=256 (A shared over l)
  k_gemv<1, false><<<1024, 256, 0, stream>>>(te, t1_w, t1_b, tt, 256, 256);
  // tp[l] = tt[l] @ t2_w[l]^T + t2_b[l]     [4,4,256], K=256 (A per-group)
  k_gemv<0, true><<<1024, 256, 0, stream>>>(tt, t2_w, t2_b, tp, 256, 256);

  k_inproj<<<4096, 256, 0, stream>>>(x, in_w, in_b, qe, h);

  for (int l = 0; l < NLAYER; l++) {
    k_decbias<<<64, 256, 0, stream>>>(relb + (size_t)l * 2047 * 8, decb);
    k_ln<<<4096, 256, 0, stream>>>(h, tp + l * 1024, n1_w + l * 256, n1_b + l * 256, xn);
    k_gemm<0, false><<<dim3(12, 64), 256, 0, stream>>>(
        xn, qkv_w + (size_t)l * 768 * 256, qkv_b + l * 768, qkvb, 4096, 768, 256);
    k_attn<<<dim3(64, 32), 256, 0, stream>>>(qkvb, decb, ob);
    k_gemm<0, true><<<dim3(4, 64), 256, 0, stream>>>(
        ob, ap_w + (size_t)l * 256 * 256, ap_b + l * 256, h, 4096, 256, 256);
    k_ln<<<4096, 256, 0, stream>>>(h, nullptr, n2_w + l * 256, n2_b + l * 256, xn);
    k_gemm<1, false><<<dim3(16, 64), 256, 0, stream>>>(
        xn, f1_w + (size_t)l * 1024 * 256, f1_b + l * 1024, y1, 4096, 1024, 256);
    k_gemm<0, true><<<dim3(4, 64), 256, 0, stream>>>(
        y1, f2_w + (size_t)l * 256 * 1024, f2_b + l * 256, h, 4096, 256, 1024);
  }
  k_out<<<256, 256, 0, stream>>>(h, out_w, out_b, out);
}

// Round 3
// 755.726 us; speedup vs baseline: 2.1714x; 1.5335x over previous
//
#include <hip/hip_runtime.h>
#include <hip/hip_bf16.h>
#include <math.h>

#define S_LEN 1024
#define HID 256
#define HEADS 8
#define HD 32
#define NLAYER 4
#define TED 256
#define BATCH 4
#define DECAY 0.1f
#define ATT_SCALE 0.17677669529663687f  // 32^-0.5

typedef __bf16 bf8_t __attribute__((ext_vector_type(8)));
typedef float f4_t __attribute__((ext_vector_type(4)));

__device__ __forceinline__ float gelu_f(float x) {
  return 0.5f * x * (1.f + erff(x * 0.70710678118654752f));
}
__device__ __forceinline__ __bf16 f2bf(float f) { return (__bf16)f; }

// ---------------------------------------------------------------- prep: emb
__global__ __launch_bounds__(256) void k_emb(const float* __restrict__ timev,
                                             float* __restrict__ emb) {
  int b = blockIdx.x, j = threadIdx.x;
  float t = timev[b];
  int i = j & 127;
  float freq = __expf(-logf(10000.f) * (float)i / 127.f);
  float a = t * freq;
  emb[b * 256 + j] = (j < 128) ? sinf(a) : cosf(a);
}

// ------------------------------------------------- wave-parallel GEMV (prep)
template <int ACT, bool APG>
__global__ __launch_bounds__(256) void k_gemv(
    const float* __restrict__ A, const float* __restrict__ W,
    const float* __restrict__ bias, float* __restrict__ out,
    int K, int OUT) {
  int r = blockIdx.x * 4 + (threadIdx.x >> 6);
  int lane = threadIdx.x & 63;
  int o = r % OUT;
  int b = (r / OUT) % BATCH;
  int g = r / (OUT * BATCH);
  const float* a = A + (size_t)((APG ? g * BATCH : 0) + b) * K;
  const float* w = W + (size_t)(g * OUT + o) * K;
  float s = 0.f;
  for (int k = lane * 4; k < K; k += 256) {
    float4 a4 = *(const float4*)(a + k);
    float4 w4 = *(const float4*)(w + k);
    s += a4.x * w4.x + a4.y * w4.y + a4.z * w4.z + a4.w * w4.w;
  }
#pragma unroll
  for (int off = 32; off; off >>= 1) s += __shfl_xor(s, off);
  if (lane == 0) {
    s += bias[g * OUT + o];
    if (ACT == 1) s = gelu_f(s);
    if (ACT == 2) {
      float sp = (s > 20.f) ? s : log1pf(__expf(s));
      s = s * tanhf(sp);
    }
    out[r] = s;
  }
}

// ------------------------------------------------------------ input projection
__global__ __launch_bounds__(256) void k_inproj(
    const float* __restrict__ x, const float* __restrict__ in_w,
    const float* __restrict__ in_b, const float* __restrict__ qe,
    float* __restrict__ h) {
  int row = blockIdx.x;
  int b = row >> 10;
  int j = threadIdx.x;
  __shared__ float xr[16];
  if (j < 16) xr[j] = x[row * 16 + j];
  __syncthreads();
  float s = in_b[j] + qe[b * 256 + j];
  const float* w = in_w + j * 16;
#pragma unroll
  for (int i = 0; i < 16; i++) s += xr[i] * w[i];
  h[(size_t)row * 256 + j] = s;
}

// -------------------------------------------------------------------- layernorm
__global__ __launch_bounds__(256) void k_ln(
    const float* __restrict__ hbuf, const float* __restrict__ tp,
    const float* __restrict__ w, const float* __restrict__ bparm,
    float* __restrict__ out) {
  int row = blockIdx.x, b = row >> 10, tid = threadIdx.x;
  float v = hbuf[(size_t)row * 256 + tid];
  if (tp) v += tp[b * 256 + tid];
  __shared__ float red[4];
  float s = v;
#pragma unroll
  for (int off = 32; off; off >>= 1) s += __shfl_xor(s, off);
  if ((tid & 63) == 0) red[tid >> 6] = s;
  __syncthreads();
  float mean = (red[0] + red[1] + red[2] + red[3]) * (1.f / 256.f);
  float d = v - mean;
  float s2 = d * d;
#pragma unroll
  for (int off = 32; off; off >>= 1) s2 += __shfl_xor(s2, off);
  __syncthreads();
  if ((tid & 63) == 0) red[tid >> 6] = s2;
  __syncthreads();
  float var = (red[0] + red[1] + red[2] + red[3]) * (1.f / 256.f);
  out[(size_t)row * 256 + tid] = d * rsqrtf(var + 1e-5f) * w[tid] + bparm[tid];
}

// ----------------------------------------------------------------------- GEMM
template <int ACT, bool ADD>
__global__ __launch_bounds__(256) void k_gemm(
    const float* __restrict__ A, const float* __restrict__ W,
    const float* __restrict__ bias, float* __restrict__ C,
    int M, int N, int K) {
  __shared__ float a_lds[16][68];
  __shared__ float b_lds[16][68];
  int tid = threadIdx.x;
  int tx = tid & 15, ty = tid >> 4;
  int m0 = blockIdx.y * 64, n0 = blockIdx.x * 64;
  float acc[4][4] = {};
  int lr = tid >> 2;
  int lc = (tid & 3) * 4;
  for (int k0 = 0; k0 < K; k0 += 16) {
    float4 av = *(const float4*)(A + (size_t)(m0 + lr) * K + k0 + lc);
    float4 wv = *(const float4*)(W + (size_t)(n0 + lr) * K + k0 + lc);
    __syncthreads();
    a_lds[lc + 0][lr] = av.x; a_lds[lc + 1][lr] = av.y;
    a_lds[lc + 2][lr] = av.z; a_lds[lc + 3][lr] = av.w;
    b_lds[lc + 0][lr] = wv.x; b_lds[lc + 1][lr] = wv.y;
    b_lds[lc + 2][lr] = wv.z; b_lds[lc + 3][lr] = wv.w;
    __syncthreads();
#pragma unroll
    for (int kk = 0; kk < 16; kk++) {
      float4 a4 = *(const float4*)&a_lds[kk][ty * 4];
      float4 b4 = *(const float4*)&b_lds[kk][tx * 4];
      acc[0][0] += a4.x * b4.x; acc[0][1] += a4.x * b4.y;
      acc[0][2] += a4.x * b4.z; acc[0][3] += a4.x * b4.w;
      acc[1][0] += a4.y * b4.x; acc[1][1] += a4.y * b4.y;
      acc[1][2] += a4.y * b4.z; acc[1][3] += a4.y * b4.w;
      acc[2][0] += a4.z * b4.x; acc[2][1] += a4.z * b4.y;
      acc[2][2] += a4.z * b4.z; acc[2][3] += a4.z * b4.w;
      acc[3][0] += a4.w * b4.x; acc[3][1] += a4.w * b4.y;
      acc[3][2] += a4.w * b4.z; acc[3][3] += a4.w * b4.w;
    }
  }
#pragma unroll
  for (int i = 0; i < 4; i++) {
#pragma unroll
    for (int j = 0; j < 4; j++) {
      int r = m0 + ty * 4 + i, c = n0 + tx * 4 + j;
      float v = acc[i][j] + bias[c];
      if (ACT == 1) v = gelu_f(v);
      size_t idx = (size_t)r * N + c;
      if (ADD) C[idx] += v; else C[idx] = v;
    }
  }
}

// --------------------------------------------------------------- decayed bias
// writes head-major: decb_t[h][idx], stride 2048
__global__ void k_decbias(const float* __restrict__ relb, float* __restrict__ decb_t) {
  int i = blockIdx.x * 256 + threadIdx.x;
  if (i < 2047 * 8) {
    int idx = i >> 3, hh = i & 7;
    float dec = __expf(-DECAY * fabsf((float)(idx - 1023)));
    decb_t[hh * 2048 + idx] = dec * relb[i];
  }
}

// ------------------------------------------------------- MFMA flash attention
// qkv: [B,S,768] ([3][H][32] in last dim), fp32. obuf: [B,S,256] fp32.
// Block: 4 waves, one (b,h), 64 q-rows (16 per wave). KV tile = 64.
__global__ __launch_bounds__(256) void k_attn(
    const float* __restrict__ qkv, const float* __restrict__ decb_t,
    float* __restrict__ obuf) {
  __shared__ __bf16 Kl[64 * 40];        // [kv][hd], stride 40 (80B, 16B-aligned rows)
  __shared__ __bf16 Vt[32 * 72];        // [d][kv], stride 72 (144B)
  __shared__ __bf16 Pl[4][16 * 72];     // per-wave P [qrow][kv], stride 72
  __shared__ float db[1088];            // decayed-bias slice

  int tid = threadIdx.x;
  int w = tid >> 6, lane = tid & 63;
  int g = lane >> 4, c = lane & 15;
  int bh = blockIdx.y;
  int b = bh >> 3, hh = bh & 7;
  int q0 = blockIdx.x * 64;

  for (int i = tid; i < 1087; i += 256) db[i] = decb_t[hh * 2048 + q0 + i];

  // Q fragment (A-operand): lane holds Q[q0 + w*16 + c][8g .. 8g+7]
  bf8_t qfrag;
  {
    const float* Qsrc = qkv + ((size_t)(b * S_LEN + q0 + w * 16 + c)) * 768 + hh * 32 + 8 * g;
    float4 qa = ((const float4*)Qsrc)[0];
    float4 qb = ((const float4*)Qsrc)[1];
    qfrag[0] = f2bf(qa.x); qfrag[1] = f2bf(qa.y); qfrag[2] = f2bf(qa.z); qfrag[3] = f2bf(qa.w);
    qfrag[4] = f2bf(qb.x); qfrag[5] = f2bf(qb.y); qfrag[6] = f2bf(qb.z); qfrag[7] = f2bf(qb.w);
  }

  float m_run[4], l_run[4];
  f4_t o0 = {0.f, 0.f, 0.f, 0.f}, o1 = {0.f, 0.f, 0.f, 0.f};
#pragma unroll
  for (int r = 0; r < 4; r++) { m_run[r] = -1e30f; l_run[r] = 0.f; }

  int rowb = w * 16 + 4 * g;          // wave-local base q-row for this lane's regs
  __bf16* Plw = &Pl[w][0];

  for (int c0 = 0; c0 < S_LEN; c0 += 64) {
    __syncthreads();
    // ---- stage K (row-major bf16) and V (transposed bf16) ----
    {
      int kvr = tid & 63, part = tid >> 6;  // part is wave-uniform
      const float* Ksrc = qkv + ((size_t)(b * S_LEN + c0 + kvr)) * 768 + 256 + hh * 32 + part * 8;
      const float* Vsrc = qkv + ((size_t)(b * S_LEN + c0 + kvr)) * 768 + 512 + hh * 32 + part * 8;
      float4 ka = ((const float4*)Ksrc)[0], kb = ((const float4*)Ksrc)[1];
      float4 va = ((const float4*)Vsrc)[0], vb = ((const float4*)Vsrc)[1];
      bf8_t k8;
      k8[0] = f2bf(ka.x); k8[1] = f2bf(ka.y); k8[2] = f2bf(ka.z); k8[3] = f2bf(ka.w);
      k8[4] = f2bf(kb.x); k8[5] = f2bf(kb.y); k8[6] = f2bf(kb.z); k8[7] = f2bf(kb.w);
      *(bf8_t*)&Kl[kvr * 40 + part * 8] = k8;
      int d0 = part * 8;
      Vt[(d0 + 0) * 72 + kvr] = f2bf(va.x); Vt[(d0 + 1) * 72 + kvr] = f2bf(va.y);
      Vt[(d0 + 2) * 72 + kvr] = f2bf(va.z); Vt[(d0 + 3) * 72 + kvr] = f2bf(va.w);
      Vt[(d0 + 4) * 72 + kvr] = f2bf(vb.x); Vt[(d0 + 5) * 72 + kvr] = f2bf(vb.y);
      Vt[(d0 + 6) * 72 + kvr] = f2bf(vb.z); Vt[(d0 + 7) * 72 + kvr] = f2bf(vb.w);
    }
    __syncthreads();

    // ---- QK^T: 4 MFMA -> S[16q x 64kv]; lane holds rows rowb+r, col j*16+c ----
    f4_t sc[4];
    f4_t zero4 = {0.f, 0.f, 0.f, 0.f};
#pragma unroll
    for (int j = 0; j < 4; j++) {
      bf8_t kfrag = *(const bf8_t*)&Kl[(j * 16 + c) * 40 + g * 8];
      sc[j] = __builtin_amdgcn_mfma_f32_16x16x32_bf16(qfrag, kfrag, zero4, 0, 0, 0);
    }
    // bias + scale, tile max
    float tm[4] = {-1e30f, -1e30f, -1e30f, -1e30f};
#pragma unroll
    for (int j = 0; j < 4; j++) {
      int bidx = rowb + 1023 - (c0 + j * 16 + c);
#pragma unroll
      for (int r = 0; r < 4; r++) {
        float x = sc[j][r] * ATT_SCALE + db[bidx + r];
        sc[j][r] = x;
        tm[r] = fmaxf(tm[r], x);
      }
    }
#pragma unroll
    for (int r = 0; r < 4; r++) {
#pragma unroll
      for (int m = 1; m < 16; m <<= 1) tm[r] = fmaxf(tm[r], __shfl_xor(tm[r], m));
    }
    float resc[4], ps[4];
#pragma unroll
    for (int r = 0; r < 4; r++) {
      float mnew = fmaxf(m_run[r], tm[r]);
      resc[r] = __expf(m_run[r] - mnew);
      m_run[r] = mnew;
      ps[r] = 0.f;
    }
    // p = exp(s - m), store to per-wave P tile (A-operand layout source)
#pragma unroll
    for (int j = 0; j < 4; j++) {
#pragma unroll
      for (int r = 0; r < 4; r++) {
        float p = __expf(sc[j][r] - m_run[r]);
        ps[r] += p;
        Plw[(4 * g + r) * 72 + j * 16 + c] = f2bf(p);
      }
    }
#pragma unroll
    for (int r = 0; r < 4; r++) {
#pragma unroll
      for (int m = 1; m < 16; m <<= 1) ps[r] += __shfl_xor(ps[r], m);
      l_run[r] = l_run[r] * resc[r] + ps[r];
      o0[r] *= resc[r];
      o1[r] *= resc[r];
    }
    // ---- PV: O[16q x 32d] += P[16q x 64kv] * V[64kv x 32d] ----
#pragma unroll
    for (int ss = 0; ss < 2; ss++) {
      bf8_t pa = *(const bf8_t*)&Plw[c * 72 + ss * 32 + g * 8];
      bf8_t v0 = *(const bf8_t*)&Vt[c * 72 + ss * 32 + g * 8];
      bf8_t v1 = *(const bf8_t*)&Vt[(c + 16) * 72 + ss * 32 + g * 8];
      o0 = __builtin_amdgcn_mfma_f32_16x16x32_bf16(pa, v0, o0, 0, 0, 0);
      o1 = __builtin_amdgcn_mfma_f32_16x16x32_bf16(pa, v1, o1, 0, 0, 0);
    }
  }

  // ---- epilogue ----
#pragma unroll
  for (int r = 0; r < 4; r++) {
    float inv = 1.f / l_run[r];
    size_t rowg = (size_t)(b * S_LEN + q0 + rowb + r);
    obuf[rowg * 256 + hh * 32 + c] = o0[r] * inv;
    obuf[rowg * 256 + hh * 32 + 16 + c] = o1[r] * inv;
  }
}

// ------------------------------------------------------------------- final out
__global__ __launch_bounds__(256) void k_out(
    const float* __restrict__ hbuf, const float* __restrict__ out_w,
    const float* __restrict__ out_b, float* __restrict__ out) {
  int tid = threadIdx.x;
  int r = blockIdx.x * 16 + (tid >> 4);
  int c = tid & 15;
  const float* hr = hbuf + (size_t)r * 256;
  const float* w = out_w + c * 256;
  float s = out_b[c];
  for (int k = 0; k < 256; k++) s += hr[k] * w[k];
  out[r * 16 + c] = s;
}

// ------------------------------------------------------------------ host side
extern "C" void kernel_launch(void* const* d_in, const int* in_sizes, int n_in,
                              void* d_out, int out_size, void* d_ws, size_t ws_size,
                              hipStream_t stream) {
  const float* x      = (const float*)d_in[0];
  const float* query  = (const float*)d_in[1];
  const float* timev  = (const float*)d_in[2];
  const float* tm_w1  = (const float*)d_in[3];
  const float* tm_b1  = (const float*)d_in[4];
  const float* tm_w2  = (const float*)d_in[5];
  const float* tm_b2  = (const float*)d_in[6];
  const float* in_w   = (const float*)d_in[7];
  const float* in_b   = (const float*)d_in[8];
  const float* q_w1   = (const float*)d_in[9];
  const float* q_b1   = (const float*)d_in[10];
  const float* q_w2   = (const float*)d_in[11];
  const float* q_b2   = (const float*)d_in[12];
  const float* n1_w   = (const float*)d_in[13];
  const float* n1_b   = (const float*)d_in[14];
  const float* qkv_w  = (const float*)d_in[15];
  const float* qkv_b  = (const float*)d_in[16];
  const float* ap_w   = (const float*)d_in[17];
  const float* ap_b   = (const float*)d_in[18];
  const float* relb   = (const float*)d_in[19];
  const float* n2_w   = (const float*)d_in[20];
  const float* n2_b   = (const float*)d_in[21];
  const float* f1_w   = (const float*)d_in[22];
  const float* f1_b   = (const float*)d_in[23];
  const float* f2_w   = (const float*)d_in[24];
  const float* f2_b   = (const float*)d_in[25];
  const float* t1_w   = (const float*)d_in[26];
  const float* t1_b   = (const float*)d_in[27];
  const float* t2_w   = (const float*)d_in[28];
  const float* t2_b   = (const float*)d_in[29];
  const float* out_w  = (const float*)d_in[30];
  const float* out_b  = (const float*)d_in[31];
  float* out = (float*)d_out;

  float* ws = (float*)d_ws;
  float* h    = ws;                       // 1M floats
  float* xn   = ws + (1u << 20);          // 1M
  float* qkvb = ws + 2 * (1u << 20);      // 3M
  float* ob   = ws + 5 * (1u << 20);      // 1M
  float* y1   = ws + 6 * (1u << 20);      // 4M
  float* decb = ws + 10 * (1u << 20);     // 8*2048 = 16384 floats (head-major)
  float* qe   = decb + 16384;             // 1024
  float* tp   = qe + 1024;                // 4*1024

  // prep scratch lives inside qkvb (unused until first k_gemm of layer 0)
  float* emb = qkvb;
  float* te1 = qkvb + 1024;
  float* te  = qkvb + 5120;
  float* q1  = qkvb + 6144;
  float* tt  = qkvb + 7168;

  k_emb<<<4, 256, 0, stream>>>(timev, emb);
  k_gemv<2, false><<<1024, 256, 0, stream>>>(emb, tm_w1, tm_b1, te1, 256, 1024);
  k_gemv<0, false><<<256, 256, 0, stream>>>(te1, tm_w2, tm_b2, te, 1024, 256);
  k_gemv<1, false><<<256, 256, 0, stream>>>(query, q_w1, q_b1, q1, 32, 256);
  k_gemv<0, false><<<256, 256, 0, stream>>>(q1, q_w2, q_b2, qe, 256, 256);
  k_gemv<1, false><<<1024, 256, 0, stream>>>(te, t1_w, t1_b, tt, 256, 256);
  k_gemv<0, true><<<1024, 256, 0, stream>>>(tt, t2_w, t2_b, tp, 256, 256);

  k_inproj<<<4096, 256, 0, stream>>>(x, in_w, in_b, qe, h);

  for (int l = 0; l < NLAYER; l++) {
    k_decbias<<<64, 256, 0, stream>>>(relb + (size_t)l * 2047 * 8, decb);
    k_ln<<<4096, 256, 0, stream>>>(h, tp + l * 1024, n1_w + l * 256, n1_b + l * 256, xn);
    k_gemm<0, false><<<dim3(12, 64), 256, 0, stream>>>(
        xn, qkv_w + (size_t)l * 768 * 256, qkv_b + l * 768, qkvb, 4096, 768, 256);
    k_attn<<<dim3(16, 32), 256, 0, stream>>>(qkvb, decb, ob);
    k_gemm<0, true><<<dim3(4, 64), 256, 0, stream>>>(
        ob, ap_w + (size_t)l * 256 * 256, ap_b + l * 256, h, 4096, 256, 256);
    k_ln<<<4096, 256, 0, stream>>>(h, nullptr, n2_w + l * 256, n2_b + l * 256, xn);
    k_gemm<1, false><<<dim3(16, 64), 256, 0, stream>>>(
        xn, f1_w + (size_t)l * 1024 * 256, f1_b + l * 1024, y1, 4096, 1024, 256);
    k_gemm<0, true><<<dim3(4, 64), 256, 0, stream>>>(
        y1, f2_w + (size_t)l * 256 * 1024, f2_b + l * 256, h, 4096, 256, 1024);
  }
  k_out<<<256, 256, 0, stream>>>(h, out_w, out_b, out);
}

// Round 4
// 486.702 us; speedup vs baseline: 3.3716x; 1.5527x over previous
//
#include <hip/hip_runtime.h>
#include <hip/hip_bf16.h>
#include <math.h>

#define S_LEN 1024
#define HID 256
#define HEADS 8
#define HD 32
#define NLAYER 4
#define TED 256
#define BATCH 4
#define DECAY 0.1f
#define ATT_SCALE 0.17677669529663687f  // 32^-0.5

typedef __bf16 bf8_t __attribute__((ext_vector_type(8)));
typedef float f4_t __attribute__((ext_vector_type(4)));

__device__ __forceinline__ float gelu_f(float x) {
  return 0.5f * x * (1.f + erff(x * 0.70710678118654752f));
}
__device__ __forceinline__ __bf16 f2bf(float f) { return (__bf16)f; }

// ---------------------------------------------------------------- prep: emb
__global__ __launch_bounds__(256) void k_emb(const float* __restrict__ timev,
                                             float* __restrict__ emb) {
  int b = blockIdx.x, j = threadIdx.x;
  float t = timev[b];
  int i = j & 127;
  float freq = __expf(-logf(10000.f) * (float)i / 127.f);
  float a = t * freq;
  emb[b * 256 + j] = (j < 128) ? sinf(a) : cosf(a);
}

// ------------------------------------------------- wave-parallel GEMV (prep)
template <int ACT, bool APG>
__global__ __launch_bounds__(256) void k_gemv(
    const float* __restrict__ A, const float* __restrict__ W,
    const float* __restrict__ bias, float* __restrict__ out,
    int K, int OUT) {
  int r = blockIdx.x * 4 + (threadIdx.x >> 6);
  int lane = threadIdx.x & 63;
  int o = r % OUT;
  int b = (r / OUT) % BATCH;
  int g = r / (OUT * BATCH);
  const float* a = A + (size_t)((APG ? g * BATCH : 0) + b) * K;
  const float* w = W + (size_t)(g * OUT + o) * K;
  float s = 0.f;
  for (int k = lane * 4; k < K; k += 256) {
    float4 a4 = *(const float4*)(a + k);
    float4 w4 = *(const float4*)(w + k);
    s += a4.x * w4.x + a4.y * w4.y + a4.z * w4.z + a4.w * w4.w;
  }
#pragma unroll
  for (int off = 32; off; off >>= 1) s += __shfl_xor(s, off);
  if (lane == 0) {
    s += bias[g * OUT + o];
    if (ACT == 1) s = gelu_f(s);
    if (ACT == 2) {
      float sp = (s > 20.f) ? s : log1pf(__expf(s));
      s = s * tanhf(sp);
    }
    out[r] = s;
  }
}

// ------------------------------------------------------------ input projection
__global__ __launch_bounds__(256) void k_inproj(
    const float* __restrict__ x, const float* __restrict__ in_w,
    const float* __restrict__ in_b, const float* __restrict__ qe,
    float* __restrict__ h) {
  int row = blockIdx.x;
  int b = row >> 10;
  int j = threadIdx.x;
  __shared__ float xr[16];
  if (j < 16) xr[j] = x[row * 16 + j];
  __syncthreads();
  float s = in_b[j] + qe[b * 256 + j];
  const float* w = in_w + j * 16;
#pragma unroll
  for (int i = 0; i < 16; i++) s += xr[i] * w[i];
  h[(size_t)row * 256 + j] = s;
}

// --------------------------------------------- layernorm (fp32 in, bf16 out)
__global__ __launch_bounds__(256) void k_ln(
    const float* __restrict__ hbuf, const float* __restrict__ tp,
    const float* __restrict__ w, const float* __restrict__ bparm,
    __bf16* __restrict__ out) {
  int row = blockIdx.x, b = row >> 10, tid = threadIdx.x;
  float v = hbuf[(size_t)row * 256 + tid];
  if (tp) v += tp[b * 256 + tid];
  __shared__ float red[4];
  float s = v;
#pragma unroll
  for (int off = 32; off; off >>= 1) s += __shfl_xor(s, off);
  if ((tid & 63) == 0) red[tid >> 6] = s;
  __syncthreads();
  float mean = (red[0] + red[1] + red[2] + red[3]) * (1.f / 256.f);
  float d = v - mean;
  float s2 = d * d;
#pragma unroll
  for (int off = 32; off; off >>= 1) s2 += __shfl_xor(s2, off);
  __syncthreads();
  if ((tid & 63) == 0) red[tid >> 6] = s2;
  __syncthreads();
  float var = (red[0] + red[1] + red[2] + red[3]) * (1.f / 256.f);
  out[(size_t)row * 256 + tid] = f2bf(d * rsqrtf(var + 1e-5f) * w[tid] + bparm[tid]);
}

// ----------------------------------------------------- fp32 -> bf16 convert
__global__ __launch_bounds__(256) void k_cvt(const float* __restrict__ in,
                                             __bf16* __restrict__ out, int n) {
  int i = (blockIdx.x * 256 + threadIdx.x) * 8;
  if (i >= n) return;
  float4 a = *(const float4*)(in + i);
  float4 b = *(const float4*)(in + i + 4);
  bf8_t o;
  o[0] = f2bf(a.x); o[1] = f2bf(a.y); o[2] = f2bf(a.z); o[3] = f2bf(a.w);
  o[4] = f2bf(b.x); o[5] = f2bf(b.y); o[6] = f2bf(b.z); o[7] = f2bf(b.w);
  *(bf8_t*)(out + i) = o;
}

// ----------------------------------------------------------- MFMA bf16 GEMM
// C[M,N] = A[M,K] @ W[N,K]^T + bias. A,W bf16; accumulate fp32.
// OUTMODE: 0 = write fp32, 1 = add into fp32, 2 = write bf16. ACT: 1 = gelu.
// Swizzled LDS: elem (row, k-seg s of 8) stored at row*32 + (s^((row>>1)&3))*8
// -> both b128 writes and frag reads are <=2-way bank conflicts (free).
template <int BM, int BN, int ACT, int OUTMODE>
__global__ __launch_bounds__(256) void k_gemm_mfma(
    const __bf16* __restrict__ A, const __bf16* __restrict__ W,
    const float* __restrict__ bias, void* __restrict__ Cv,
    int M, int N, int K) {
  constexpr int WAVE_M = BM / 2, WAVE_N = BN / 2;
  constexpr int MI = WAVE_M / 16, NJ = WAVE_N / 16;
  constexpr int AQ = BM / 64, BQ = BN / 64;
  __shared__ __bf16 Al[BM * 32];
  __shared__ __bf16 Bl[BN * 32];
  int tid = threadIdx.x;
  int w = tid >> 6, lane = tid & 63;
  int g = lane >> 4, c = lane & 15;
  int n0 = blockIdx.x * BN, m0 = blockIdx.y * BM;
  int wr = (w >> 1) * WAVE_M, wc = (w & 1) * WAVE_N;
  int srow = tid >> 2;                            // 0..63
  int scol = (tid & 3) * 8;                       // k elem offset for staging
  int sw = (((tid & 3) ^ ((tid >> 3) & 3))) * 8;  // swizzled seg (elems)
  int aseg = ((g ^ ((c >> 1) & 3))) * 8;          // frag-read swizzled seg

  f4_t acc[MI][NJ];
#pragma unroll
  for (int i = 0; i < MI; i++)
#pragma unroll
    for (int j = 0; j < NJ; j++) acc[i][j] = (f4_t){0.f, 0.f, 0.f, 0.f};

  const __bf16* Ab = A + (size_t)m0 * K + scol;
  const __bf16* Wb = W + (size_t)n0 * K + scol;

  for (int k0 = 0; k0 < K; k0 += 32) {
    bf8_t areg[AQ], breg[BQ];
#pragma unroll
    for (int q = 0; q < AQ; q++)
      areg[q] = *(const bf8_t*)(Ab + (size_t)(q * 64 + srow) * K + k0);
#pragma unroll
    for (int q = 0; q < BQ; q++)
      breg[q] = *(const bf8_t*)(Wb + (size_t)(q * 64 + srow) * K + k0);
    __syncthreads();
#pragma unroll
    for (int q = 0; q < AQ; q++)
      *(bf8_t*)&Al[(q * 64 + srow) * 32 + sw] = areg[q];
#pragma unroll
    for (int q = 0; q < BQ; q++)
      *(bf8_t*)&Bl[(q * 64 + srow) * 32 + sw] = breg[q];
    __syncthreads();
    bf8_t af[MI], bfr[NJ];
#pragma unroll
    for (int i = 0; i < MI; i++)
      af[i] = *(const bf8_t*)&Al[(wr + i * 16 + c) * 32 + aseg];
#pragma unroll
    for (int j = 0; j < NJ; j++)
      bfr[j] = *(const bf8_t*)&Bl[(wc + j * 16 + c) * 32 + aseg];
#pragma unroll
    for (int i = 0; i < MI; i++)
#pragma unroll
      for (int j = 0; j < NJ; j++)
        acc[i][j] = __builtin_amdgcn_mfma_f32_16x16x32_bf16(af[i], bfr[j], acc[i][j], 0, 0, 0);
  }
  // epilogue: C/D layout col=lane&15, row=4*(lane>>4)+reg
#pragma unroll
  for (int j = 0; j < NJ; j++) {
    int col = n0 + wc + j * 16 + c;
    float bv = bias[col];
#pragma unroll
    for (int i = 0; i < MI; i++) {
#pragma unroll
      for (int r = 0; r < 4; r++) {
        int row = m0 + wr + i * 16 + 4 * g + r;
        float v = acc[i][j][r] + bv;
        if (ACT == 1) v = gelu_f(v);
        size_t idx = (size_t)row * N + col;
        if (OUTMODE == 0) ((float*)Cv)[idx] = v;
        else if (OUTMODE == 1) ((float*)Cv)[idx] += v;
        else ((__bf16*)Cv)[idx] = f2bf(v);
      }
    }
  }
}

// --------------------------------------------------------------- decayed bias
// writes head-major: decb_t[h][idx], stride 2048
__global__ void k_decbias(const float* __restrict__ relb, float* __restrict__ decb_t) {
  int i = blockIdx.x * 256 + threadIdx.x;
  if (i < 2047 * 8) {
    int idx = i >> 3, hh = i & 7;
    float dec = __expf(-DECAY * fabsf((float)(idx - 1023)));
    decb_t[hh * 2048 + idx] = dec * relb[i];
  }
}

// ------------------------------------------------------- MFMA flash attention
// qkv: [B,S,768] bf16 ([3][H][32] in last dim). obuf: [B,S,256] bf16.
// Block: 4 waves, one (b,h), 64 q-rows (16 per wave). KV tile = 64.
__global__ __launch_bounds__(256) void k_attn(
    const __bf16* __restrict__ qkv, const float* __restrict__ decb_t,
    __bf16* __restrict__ obuf) {
  __shared__ __bf16 Kl[64 * 40];        // [kv][hd], stride 40
  __shared__ __bf16 Vt[32 * 72];        // [d][kv], stride 72
  __shared__ __bf16 Pl[4][16 * 72];     // per-wave P [qrow][kv], stride 72
  __shared__ float db[1088];

  int tid = threadIdx.x;
  int w = tid >> 6, lane = tid & 63;
  int g = lane >> 4, c = lane & 15;
  int bh = blockIdx.y;
  int b = bh >> 3, hh = bh & 7;
  int q0 = blockIdx.x * 64;

  for (int i = tid; i < 1087; i += 256) db[i] = decb_t[hh * 2048 + q0 + i];

  bf8_t qfrag = *(const bf8_t*)(qkv + ((size_t)(b * S_LEN + q0 + w * 16 + c)) * 768 + hh * 32 + 8 * g);

  float m_run[4], l_run[4];
  f4_t o0 = {0.f, 0.f, 0.f, 0.f}, o1 = {0.f, 0.f, 0.f, 0.f};
#pragma unroll
  for (int r = 0; r < 4; r++) { m_run[r] = -1e30f; l_run[r] = 0.f; }

  int rowb = w * 16 + 4 * g;
  __bf16* Plw = &Pl[w][0];

  for (int c0 = 0; c0 < S_LEN; c0 += 64) {
    __syncthreads();
    {
      int kvr = tid & 63, part = tid >> 6;  // part wave-uniform
      const __bf16* base = qkv + ((size_t)(b * S_LEN + c0 + kvr)) * 768 + hh * 32 + part * 8;
      bf8_t k8 = *(const bf8_t*)(base + 256);
      bf8_t v8 = *(const bf8_t*)(base + 512);
      *(bf8_t*)&Kl[kvr * 40 + part * 8] = k8;
      int d0s = part * 8;
#pragma unroll
      for (int jj = 0; jj < 8; jj++) Vt[(d0s + jj) * 72 + kvr] = v8[jj];
    }
    __syncthreads();

    f4_t sc[4];
    f4_t zero4 = {0.f, 0.f, 0.f, 0.f};
#pragma unroll
    for (int j = 0; j < 4; j++) {
      bf8_t kfrag = *(const bf8_t*)&Kl[(j * 16 + c) * 40 + g * 8];
      sc[j] = __builtin_amdgcn_mfma_f32_16x16x32_bf16(qfrag, kfrag, zero4, 0, 0, 0);
    }
    float tm[4] = {-1e30f, -1e30f, -1e30f, -1e30f};
#pragma unroll
    for (int j = 0; j < 4; j++) {
      int bidx = rowb + 1023 - (c0 + j * 16 + c);
#pragma unroll
      for (int r = 0; r < 4; r++) {
        float x = sc[j][r] * ATT_SCALE + db[bidx + r];
        sc[j][r] = x;
        tm[r] = fmaxf(tm[r], x);
      }
    }
#pragma unroll
    for (int r = 0; r < 4; r++) {
#pragma unroll
      for (int m = 1; m < 16; m <<= 1) tm[r] = fmaxf(tm[r], __shfl_xor(tm[r], m));
    }
    float resc[4], ps[4];
#pragma unroll
    for (int r = 0; r < 4; r++) {
      float mnew = fmaxf(m_run[r], tm[r]);
      resc[r] = __expf(m_run[r] - mnew);
      m_run[r] = mnew;
      ps[r] = 0.f;
    }
#pragma unroll
    for (int j = 0; j < 4; j++) {
#pragma unroll
      for (int r = 0; r < 4; r++) {
        float p = __expf(sc[j][r] - m_run[r]);
        ps[r] += p;
        Plw[(4 * g + r) * 72 + j * 16 + c] = f2bf(p);
      }
    }
#pragma unroll
    for (int r = 0; r < 4; r++) {
#pragma unroll
      for (int m = 1; m < 16; m <<= 1) ps[r] += __shfl_xor(ps[r], m);
      l_run[r] = l_run[r] * resc[r] + ps[r];
      o0[r] *= resc[r];
      o1[r] *= resc[r];
    }
#pragma unroll
    for (int ss = 0; ss < 2; ss++) {
      bf8_t pa = *(const bf8_t*)&Plw[c * 72 + ss * 32 + g * 8];
      bf8_t v0 = *(const bf8_t*)&Vt[c * 72 + ss * 32 + g * 8];
      bf8_t v1 = *(const bf8_t*)&Vt[(c + 16) * 72 + ss * 32 + g * 8];
      o0 = __builtin_amdgcn_mfma_f32_16x16x32_bf16(pa, v0, o0, 0, 0, 0);
      o1 = __builtin_amdgcn_mfma_f32_16x16x32_bf16(pa, v1, o1, 0, 0, 0);
    }
  }

#pragma unroll
  for (int r = 0; r < 4; r++) {
    float inv = 1.f / l_run[r];
    size_t rowg = (size_t)(b * S_LEN + q0 + rowb + r);
    obuf[rowg * 256 + hh * 32 + c] = f2bf(o0[r] * inv);
    obuf[rowg * 256 + hh * 32 + 16 + c] = f2bf(o1[r] * inv);
  }
}

// ------------------------------------------------------------------- final out
__global__ __launch_bounds__(256) void k_out(
    const float* __restrict__ hbuf, const float* __restrict__ out_w,
    const float* __restrict__ out_b, float* __restrict__ out) {
  int tid = threadIdx.x;
  int r = blockIdx.x * 16 + (tid >> 4);
  int c = tid & 15;
  const float* hr = hbuf + (size_t)r * 256;
  const float* w = out_w + c * 256;
  float s = out_b[c];
  for (int k = 0; k < 256; k++) s += hr[k] * w[k];
  out[r * 16 + c] = s;
}

// ------------------------------------------------------------------ host side
extern "C" void kernel_launch(void* const* d_in, const int* in_sizes, int n_in,
                              void* d_out, int out_size, void* d_ws, size_t ws_size,
                              hipStream_t stream) {
  const float* x      = (const float*)d_in[0];
  const float* query  = (const float*)d_in[1];
  const float* timev  = (const float*)d_in[2];
  const float* tm_w1  = (const float*)d_in[3];
  const float* tm_b1  = (const float*)d_in[4];
  const float* tm_w2  = (const float*)d_in[5];
  const float* tm_b2  = (const float*)d_in[6];
  const float* in_w   = (const float*)d_in[7];
  const float* in_b   = (const float*)d_in[8];
  const float* q_w1   = (const float*)d_in[9];
  const float* q_b1   = (const float*)d_in[10];
  const float* q_w2   = (const float*)d_in[11];
  const float* q_b2   = (const float*)d_in[12];
  const float* n1_w   = (const float*)d_in[13];
  const float* n1_b   = (const float*)d_in[14];
  const float* qkv_w  = (const float*)d_in[15];
  const float* qkv_b  = (const float*)d_in[16];
  const float* ap_w   = (const float*)d_in[17];
  const float* ap_b   = (const float*)d_in[18];
  const float* relb   = (const float*)d_in[19];
  const float* n2_w   = (const float*)d_in[20];
  const float* n2_b   = (const float*)d_in[21];
  const float* f1_w   = (const float*)d_in[22];
  const float* f1_b   = (const float*)d_in[23];
  const float* f2_w   = (const float*)d_in[24];
  const float* f2_b   = (const float*)d_in[25];
  const float* t1_w   = (const float*)d_in[26];
  const float* t1_b   = (const float*)d_in[27];
  const float* t2_w   = (const float*)d_in[28];
  const float* t2_b   = (const float*)d_in[29];
  const float* out_w  = (const float*)d_in[30];
  const float* out_b  = (const float*)d_in[31];
  float* out = (float*)d_out;

  float* ws = (float*)d_ws;
  float*  h    = ws;                                   // 1048576 f
  __bf16* xnb  = (__bf16*)(ws + 1048576);              // 4096x256 bf16
  __bf16* qkvb = (__bf16*)(ws + 1572864);              // 4096x768 bf16
  __bf16* obb  = (__bf16*)(ws + 3145728);              // 4096x256 bf16
  __bf16* y1b  = (__bf16*)(ws + 3670016);              // 4096x1024 bf16
  __bf16* wqkv = (__bf16*)(ws + 5767168);              // 4x768x256 bf16
  __bf16* wap  = (__bf16*)(ws + 6160384);              // 4x256x256 bf16
  __bf16* wf1  = (__bf16*)(ws + 6291456);              // 4x1024x256 bf16
  __bf16* wf2  = (__bf16*)(ws + 6815744);              // 4x256x1024 bf16
  float* decb  = ws + 7340032;                         // 8x2048
  float* qe    = decb + 16384;
  float* tp    = qe + 1024;
  float* emb   = tp + 4096;
  float* te1   = emb + 1024;
  float* te    = te1 + 4096;
  float* q1    = te + 1024;
  float* tt    = q1 + 1024;

  // weight conversion (independent of everything else)
  k_cvt<<<384, 256, 0, stream>>>(qkv_w, wqkv, 786432);
  k_cvt<<<128, 256, 0, stream>>>(ap_w, wap, 262144);
  k_cvt<<<512, 256, 0, stream>>>(f1_w, wf1, 1048576);
  k_cvt<<<512, 256, 0, stream>>>(f2_w, wf2, 1048576);

  // prep pipeline
  k_emb<<<4, 256, 0, stream>>>(timev, emb);
  k_gemv<2, false><<<1024, 256, 0, stream>>>(emb, tm_w1, tm_b1, te1, 256, 1024);
  k_gemv<0, false><<<256, 256, 0, stream>>>(te1, tm_w2, tm_b2, te, 1024, 256);
  k_gemv<1, false><<<256, 256, 0, stream>>>(query, q_w1, q_b1, q1, 32, 256);
  k_gemv<0, false><<<256, 256, 0, stream>>>(q1, q_w2, q_b2, qe, 256, 256);
  k_gemv<1, false><<<1024, 256, 0, stream>>>(te, t1_w, t1_b, tt, 256, 256);
  k_gemv<0, true><<<1024, 256, 0, stream>>>(tt, t2_w, t2_b, tp, 256, 256);

  k_inproj<<<4096, 256, 0, stream>>>(x, in_w, in_b, qe, h);

  for (int l = 0; l < NLAYER; l++) {
    k_decbias<<<64, 256, 0, stream>>>(relb + (size_t)l * 2047 * 8, decb);
    k_ln<<<4096, 256, 0, stream>>>(h, tp + l * 1024, n1_w + l * 256, n1_b + l * 256, xnb);
    k_gemm_mfma<128, 128, 0, 2><<<dim3(6, 32), 256, 0, stream>>>(
        xnb, wqkv + (size_t)l * 196608, qkv_b + l * 768, qkvb, 4096, 768, 256);
    k_attn<<<dim3(16, 32), 256, 0, stream>>>(qkvb, decb, obb);
    k_gemm_mfma<64, 128, 0, 1><<<dim3(2, 64), 256, 0, stream>>>(
        obb, wap + (size_t)l * 65536, ap_b + l * 256, h, 4096, 256, 256);
    k_ln<<<4096, 256, 0, stream>>>(h, nullptr, n2_w + l * 256, n2_b + l * 256, xnb);
    k_gemm_mfma<128, 128, 1, 2><<<dim3(8, 32), 256, 0, stream>>>(
        xnb, wf1 + (size_t)l * 262144, f1_b + l * 1024, y1b, 4096, 1024, 256);
    k_gemm_mfma<64, 128, 0, 1><<<dim3(2, 64), 256, 0, stream>>>(
        y1b, wf2 + (size_t)l * 262144, f2_b + l * 256, h, 4096, 256, 1024);
  }
  k_out<<<256, 256, 0, stream>>>(h, out_w, out_b, out);
}